// Round 3
// baseline (375.821 us; speedup 1.0000x reference)
//
#include <hip/hip_runtime.h>
#include <hip/hip_bf16.h>

#define TB 16
#define TS 1024
#define TQ 8
#define TL 512
#define TD 128

typedef __attribute__((ext_vector_type(8))) short bf16x8;
typedef __attribute__((ext_vector_type(4))) short short4v;
typedef __attribute__((ext_vector_type(4))) float f32x4;
typedef __attribute__((ext_vector_type(4))) float float4v;

__device__ __forceinline__ short f2bf(float f) {
    union { float fv; unsigned u; } v; v.fv = f;
    unsigned r = v.u + 0x7fffu + ((v.u >> 16) & 1u);
    return (short)(r >> 16);
}

// ---------------- ws layout (bytes) ----------------
#define OFF_Q   0u                       // q bf16 [B][S][128]        = 4 MiB
#define OFF_K   (4u << 20)               // k bf16 [B*Q][512][128]    = 16 MiB
#define OFF_V   (OFF_K + (16u << 20))    // v frag-interleaved        = 16 MiB
#define OFF_ATT (OFF_V + (16u << 20))    // attn bf16 [B][S][128]     = 4 MiB
#define OFF_W   (OFF_ATT + (4u << 20))   // 4x W^T bf16 [128][128]    = 128 KiB

// ---------------- kernel 0: transpose weights to [e][k] bf16 ----------------
__global__ void prep_w(const float* __restrict__ Wq, const float* __restrict__ Wk,
                       const float* __restrict__ Wv, const float* __restrict__ Wo,
                       short* __restrict__ wt) {
    const float* srcs[4] = {Wq, Wk, Wv, Wo};
    const float* s = srcs[blockIdx.x];
    short* dst = wt + blockIdx.x * (TD * TD);
    for (int i = threadIdx.x; i < TD * TD; i += blockDim.x) {
        int k = i >> 7, e = i & 127;           // coalesced read W[k][e]
        dst[e * TD + k] = f2bf(s[i]);          // scattered 2B write (tiny matrix)
    }
}

// ---------------- kernel 1: q projection, bf16 row-major out ----------------
__global__ __launch_bounds__(256) void proj_rm(const float* __restrict__ X,
                                               const short* __restrict__ Wt,
                                               const float* __restrict__ bias,
                                               short* __restrict__ Y) {
    __shared__ short xt[32][136];              // +8 pad: 2-way banks max
    const int t = threadIdx.x;
    const int lane = t & 63, w = t >> 6;
    const int lane16 = lane & 15, g = lane >> 4;
    const int r0 = blockIdx.x * 32;

#pragma unroll
    for (int it = 0; it < 4; ++it) {
        int f4 = t + it * 256;
        int row = f4 >> 5, col = (f4 & 31) * 4;
        float4v x = *reinterpret_cast<const float4v*>(&X[(long)(r0 + row) * TD + col]);
        short4v s;
        s[0] = f2bf(x[0]); s[1] = f2bf(x[1]); s[2] = f2bf(x[2]); s[3] = f2bf(x[3]);
        *reinterpret_cast<short4v*>(&xt[row][col]) = s;
    }
    __syncthreads();

    const int n0 = w * 32;
    bf16x8 a[2][4];
#pragma unroll
    for (int mi = 0; mi < 2; ++mi)
#pragma unroll
        for (int kt = 0; kt < 4; ++kt)
            a[mi][kt] = *reinterpret_cast<const bf16x8*>(&xt[mi * 16 + lane16][kt * 32 + g * 8]);

    const f32x4 Z = {0.f, 0.f, 0.f, 0.f};
    f32x4 acc[2][2] = {{Z, Z}, {Z, Z}};
#pragma unroll
    for (int ni = 0; ni < 2; ++ni)
#pragma unroll
        for (int kt = 0; kt < 4; ++kt) {
            bf16x8 b = *reinterpret_cast<const bf16x8*>(
                &Wt[(n0 + ni * 16 + lane16) * TD + kt * 32 + g * 8]);
#pragma unroll
            for (int mi = 0; mi < 2; ++mi)
                acc[mi][ni] = __builtin_amdgcn_mfma_f32_16x16x32_bf16(a[mi][kt], b, acc[mi][ni], 0, 0, 0);
        }

#pragma unroll
    for (int mi = 0; mi < 2; ++mi)
#pragma unroll
        for (int ni = 0; ni < 2; ++ni) {
            int e = n0 + ni * 16 + lane16;
            float bb = bias[e];
#pragma unroll
            for (int reg = 0; reg < 4; ++reg) {
                int row = r0 + mi * 16 + g * 4 + reg;
                Y[(long)row * TD + e] = f2bf(acc[mi][ni][reg] + bb);
            }
        }
}

// ---------------- kernel 2: fused k+v projection ----------------
// k -> bf16 row-major [bq][l][e]; v -> MFMA-fragment-interleaved layout:
//   elem(V[l][e]) at ((((l>>5)*8 + (e>>4))*4 + ((l>>3)&3))*16 + (e&15))*8 + (l&7)
__global__ __launch_bounds__(256) void proj_kv(const float* __restrict__ X,
                                               const short* __restrict__ Wtk,
                                               const float* __restrict__ biask,
                                               const short* __restrict__ Wtv,
                                               const float* __restrict__ biasv,
                                               short* __restrict__ K,
                                               short* __restrict__ Vf) {
    __shared__ short xt[32][136];
    const int t = threadIdx.x;
    const int lane = t & 63, w = t >> 6;
    const int lane16 = lane & 15, g = lane >> 4;
    const int r0 = blockIdx.x * 32;

#pragma unroll
    for (int it = 0; it < 4; ++it) {
        int f4 = t + it * 256;
        int row = f4 >> 5, col = (f4 & 31) * 4;
        float4v x = *reinterpret_cast<const float4v*>(&X[(long)(r0 + row) * TD + col]);
        short4v s;
        s[0] = f2bf(x[0]); s[1] = f2bf(x[1]); s[2] = f2bf(x[2]); s[3] = f2bf(x[3]);
        *reinterpret_cast<short4v*>(&xt[row][col]) = s;
    }
    __syncthreads();

    const int n0 = w * 32;
    bf16x8 a[2][4];
#pragma unroll
    for (int mi = 0; mi < 2; ++mi)
#pragma unroll
        for (int kt = 0; kt < 4; ++kt)
            a[mi][kt] = *reinterpret_cast<const bf16x8*>(&xt[mi * 16 + lane16][kt * 32 + g * 8]);

    const f32x4 Z = {0.f, 0.f, 0.f, 0.f};
    f32x4 ak[2][2] = {{Z, Z}, {Z, Z}};
    f32x4 av[2][2] = {{Z, Z}, {Z, Z}};
#pragma unroll
    for (int ni = 0; ni < 2; ++ni)
#pragma unroll
        for (int kt = 0; kt < 4; ++kt) {
            bf16x8 bk = *reinterpret_cast<const bf16x8*>(
                &Wtk[(n0 + ni * 16 + lane16) * TD + kt * 32 + g * 8]);
            bf16x8 bv = *reinterpret_cast<const bf16x8*>(
                &Wtv[(n0 + ni * 16 + lane16) * TD + kt * 32 + g * 8]);
#pragma unroll
            for (int mi = 0; mi < 2; ++mi) {
                ak[mi][ni] = __builtin_amdgcn_mfma_f32_16x16x32_bf16(a[mi][kt], bk, ak[mi][ni], 0, 0, 0);
                av[mi][ni] = __builtin_amdgcn_mfma_f32_16x16x32_bf16(a[mi][kt], bv, av[mi][ni], 0, 0, 0);
            }
        }

#pragma unroll
    for (int mi = 0; mi < 2; ++mi)
#pragma unroll
        for (int ni = 0; ni < 2; ++ni) {
            int e = n0 + ni * 16 + lane16;
            float bbk = biask[e], bbv = biasv[e];
            // K: row-major
#pragma unroll
            for (int reg = 0; reg < 4; ++reg) {
                int row = r0 + mi * 16 + g * 4 + reg;
                K[(long)row * TD + e] = f2bf(ak[mi][ni][reg] + bbk);
            }
            // V: frag-interleaved (lane holds 4 consecutive l for fixed e)
            int row0 = r0 + mi * 16 + g * 4;   // global source row
            int bq = row0 >> 9;                // /512
            int l = row0 & 511;
            int k32 = l >> 5, j8 = (l >> 3) & 3, jb = l & 7;
            long off = (long)bq * (TL * TD) +
                       ((((long)(k32 * 8 + (e >> 4)) * 4 + j8) * 16) + (e & 15)) * 8 + jb;
            short4v sv;
#pragma unroll
            for (int reg = 0; reg < 4; ++reg) sv[reg] = f2bf(av[mi][ni][reg] + bbv);
            *reinterpret_cast<short4v*>(&Vf[off]) = sv;
        }
}

// ---------------- kernel 3: fused attention ----------------
// block = (b, 16 s-rows); waves split l (scores) and e (PV); out acc across q.
__global__ __launch_bounds__(256) void attn_k(const short* __restrict__ qb,
                                              const short* __restrict__ kb,
                                              const short* __restrict__ vf,
                                              short* __restrict__ attn) {
    __shared__ float sc[16][516];   // scores f32, +4 pad
    __shared__ short pb[16][520];   // P bf16, +8 pad
    const int t = threadIdx.x;
    const int lane = t & 63, w = t >> 6;
    const int lane16 = lane & 15, g = lane >> 4;
    const int b = blockIdx.y, s0 = blockIdx.x * 16;

    // Q fragments (A operand), held for whole kernel
    bf16x8 aq[4];
    const short* qrow = qb + (long)(b * TS + s0 + lane16) * TD;
#pragma unroll
    for (int kt = 0; kt < 4; ++kt)
        aq[kt] = *reinterpret_cast<const bf16x8*>(&qrow[kt * 32 + g * 8]);

    const f32x4 Z = {0.f, 0.f, 0.f, 0.f};
    f32x4 o[2] = {Z, Z};
    const float kSc = 0.08838834764831845f * 1.4426950408889634f; // 1/sqrt(128) * log2(e)

    for (int qi = 0; qi < TQ; ++qi) {
        const long kvb = (long)(b * TQ + qi) * (TL * TD);

        // ---- scores: wave w owns l in [w*128, w*128+128) ----
        f32x4 sacc[8];
#pragma unroll
        for (int ni = 0; ni < 8; ++ni) sacc[ni] = Z;
#pragma unroll
        for (int ni = 0; ni < 8; ++ni) {
            int l = w * 128 + ni * 16 + lane16;
            const short* krow = kb + kvb + (long)l * TD;
#pragma unroll
            for (int kt = 0; kt < 4; ++kt) {
                bf16x8 bk = *reinterpret_cast<const bf16x8*>(&krow[kt * 32 + g * 8]);
                sacc[ni] = __builtin_amdgcn_mfma_f32_16x16x32_bf16(aq[kt], bk, sacc[ni], 0, 0, 0);
            }
        }
#pragma unroll
        for (int ni = 0; ni < 8; ++ni)
#pragma unroll
            for (int reg = 0; reg < 4; ++reg)
                sc[g * 4 + reg][w * 128 + ni * 16 + lane16] = sacc[ni][reg];
        __syncthreads();

        // ---- softmax over l: 16 threads per row ----
        {
            int row = t >> 4, sub = t & 15;
            float p[32];
            float mx = -1e30f;
#pragma unroll
            for (int i = 0; i < 32; ++i) { p[i] = sc[row][sub + i * 16]; mx = fmaxf(mx, p[i]); }
#pragma unroll
            for (int off = 1; off < 16; off <<= 1) mx = fmaxf(mx, __shfl_xor(mx, off));
            float sum = 0.f;
#pragma unroll
            for (int i = 0; i < 32; ++i) { p[i] = exp2f((p[i] - mx) * kSc); sum += p[i]; }
#pragma unroll
            for (int off = 1; off < 16; off <<= 1) sum += __shfl_xor(sum, off);
            float inv = 1.f / sum;
#pragma unroll
            for (int i = 0; i < 32; ++i) pb[row][sub + i * 16] = f2bf(p[i] * inv);
        }
        __syncthreads();

        // ---- PV: wave w owns e in [w*32, w*32+32); accumulate over q ----
#pragma unroll
        for (int kt = 0; kt < 16; ++kt) {
            bf16x8 pa = *reinterpret_cast<const bf16x8*>(&pb[lane16][kt * 32 + g * 8]);
#pragma unroll
            for (int ni = 0; ni < 2; ++ni) {
                int e0 = w * 32 + ni * 16;
                const short* vp = vf + kvb + ((long)((kt * 8 + (e0 >> 4)) * 4 + g) * 16 + lane16) * 8;
                bf16x8 bv = *reinterpret_cast<const bf16x8*>(vp);
                o[ni] = __builtin_amdgcn_mfma_f32_16x16x32_bf16(pa, bv, o[ni], 0, 0, 0);
            }
        }
        // pb protected by next iteration's first barrier; sc by this one. No barrier here.
    }

    // ---- epilogue: attn bf16 row-major ----
#pragma unroll
    for (int ni = 0; ni < 2; ++ni) {
        int e = w * 32 + ni * 16 + lane16;
#pragma unroll
        for (int reg = 0; reg < 4; ++reg) {
            int s = s0 + g * 4 + reg;
            attn[(long)(b * TS + s) * TD + e] = f2bf(o[ni][reg]);
        }
    }
}

// ---------------- kernel 4: output projection, f32 out ----------------
__global__ __launch_bounds__(256) void final_proj(const short* __restrict__ A,
                                                  const short* __restrict__ Wt,
                                                  const float* __restrict__ bias,
                                                  float* __restrict__ out) {
    const int t = threadIdx.x;
    const int lane = t & 63, w = t >> 6;
    const int lane16 = lane & 15, g = lane >> 4;
    const int r0 = blockIdx.x * 32;
    const int n0 = w * 32;

    bf16x8 a[2][4];
#pragma unroll
    for (int mi = 0; mi < 2; ++mi)
#pragma unroll
        for (int kt = 0; kt < 4; ++kt)
            a[mi][kt] = *reinterpret_cast<const bf16x8*>(
                &A[(long)(r0 + mi * 16 + lane16) * TD + kt * 32 + g * 8]);

    const f32x4 Z = {0.f, 0.f, 0.f, 0.f};
    f32x4 acc[2][2] = {{Z, Z}, {Z, Z}};
#pragma unroll
    for (int ni = 0; ni < 2; ++ni)
#pragma unroll
        for (int kt = 0; kt < 4; ++kt) {
            bf16x8 b = *reinterpret_cast<const bf16x8*>(
                &Wt[(n0 + ni * 16 + lane16) * TD + kt * 32 + g * 8]);
#pragma unroll
            for (int mi = 0; mi < 2; ++mi)
                acc[mi][ni] = __builtin_amdgcn_mfma_f32_16x16x32_bf16(a[mi][kt], b, acc[mi][ni], 0, 0, 0);
        }

#pragma unroll
    for (int mi = 0; mi < 2; ++mi)
#pragma unroll
        for (int ni = 0; ni < 2; ++ni) {
            int e = n0 + ni * 16 + lane16;
            float bb = bias[e];
#pragma unroll
            for (int reg = 0; reg < 4; ++reg) {
                int row = r0 + mi * 16 + g * 4 + reg;
                out[(long)row * TD + e] = acc[mi][ni][reg] + bb;
            }
        }
}

extern "C" void kernel_launch(void* const* d_in, const int* in_sizes, int n_in,
                              void* d_out, int out_size, void* d_ws, size_t ws_size,
                              hipStream_t stream) {
    (void)in_sizes; (void)n_in; (void)out_size; (void)ws_size;
    const float* target = (const float*)d_in[0];
    const float* source = (const float*)d_in[1];
    const float* Wq = (const float*)d_in[2];
    const float* bq = (const float*)d_in[3];
    const float* Wk = (const float*)d_in[4];
    const float* bk = (const float*)d_in[5];
    const float* Wv = (const float*)d_in[6];
    const float* bv = (const float*)d_in[7];
    const float* Wo = (const float*)d_in[8];
    const float* bo = (const float*)d_in[9];

    char* ws = (char*)d_ws;
    short* qb = (short*)(ws + OFF_Q);
    short* kb = (short*)(ws + OFF_K);
    short* vf = (short*)(ws + OFF_V);
    short* at = (short*)(ws + OFF_ATT);
    short* wt = (short*)(ws + OFF_W);
    float* out = (float*)d_out;

    prep_w<<<4, 256, 0, stream>>>(Wq, Wk, Wv, Wo, wt);
    proj_rm<<<(TB * TS) / 32, 256, 0, stream>>>(target, wt + 0 * TD * TD, bq, qb);
    proj_kv<<<(TB * TQ * TL) / 32, 256, 0, stream>>>(source, wt + 1 * TD * TD, bk,
                                                     wt + 2 * TD * TD, bv, kb, vf);
    dim3 g3(TS / 16, TB);
    attn_k<<<g3, 256, 0, stream>>>(qb, kb, vf, at);
    final_proj<<<(TB * TS) / 32, 256, 0, stream>>>(at, wt + 3 * TD * TD, bo, out);
}

// Round 4
// 237.400 us; speedup vs baseline: 1.5831x; 1.5831x over previous
//
#include <hip/hip_runtime.h>
#include <hip/hip_bf16.h>

#define TB 16
#define TS 1024
#define TQ 8
#define TL 512
#define TD 128

typedef __attribute__((ext_vector_type(8))) short bf16x8;
typedef __attribute__((ext_vector_type(4))) short short4v;
typedef __attribute__((ext_vector_type(4))) float f32x4;
typedef __attribute__((ext_vector_type(4))) float float4v;

__device__ __forceinline__ short f2bf(float f) {
    union { float fv; unsigned u; } v; v.fv = f;
    unsigned r = v.u + 0x7fffu + ((v.u >> 16) & 1u);
    return (short)(r >> 16);
}

// ---------------- ws layout (bytes) ----------------
#define OFF_Q   0u                       // q bf16 [B][S][128]        = 4 MiB
#define OFF_K   (4u << 20)               // k bf16 [B*Q][512][128]    = 16 MiB
#define OFF_V   (OFF_K + (16u << 20))    // v frag-interleaved        = 16 MiB
#define OFF_ATT (OFF_V + (16u << 20))    // attn bf16 [B][S][128]     = 4 MiB
#define OFF_W   (OFF_ATT + (4u << 20))   // 4x W^T bf16 [128][128]    = 128 KiB

// ---------------- kernel 0: transpose weights to [e][k] bf16 ----------------
__global__ void prep_w(const float* __restrict__ Wq, const float* __restrict__ Wk,
                       const float* __restrict__ Wv, const float* __restrict__ Wo,
                       short* __restrict__ wt) {
    const float* srcs[4] = {Wq, Wk, Wv, Wo};
    const float* s = srcs[blockIdx.x];
    short* dst = wt + blockIdx.x * (TD * TD);
    for (int i = threadIdx.x; i < TD * TD; i += blockDim.x) {
        int k = i >> 7, e = i & 127;           // coalesced read W[k][e]
        dst[e * TD + k] = f2bf(s[i]);          // scattered 2B write (tiny matrix)
    }
}

// ---------------- kernel 1: q projection, bf16 row-major out ----------------
__global__ __launch_bounds__(256) void proj_rm(const float* __restrict__ X,
                                               const short* __restrict__ Wt,
                                               const float* __restrict__ bias,
                                               short* __restrict__ Y) {
    __shared__ short xt[32][136];              // +8 pad: 2-way banks max
    const int t = threadIdx.x;
    const int lane = t & 63, w = t >> 6;
    const int lane16 = lane & 15, g = lane >> 4;
    const int r0 = blockIdx.x * 32;

#pragma unroll
    for (int it = 0; it < 4; ++it) {
        int f4 = t + it * 256;
        int row = f4 >> 5, col = (f4 & 31) * 4;
        float4v x = *reinterpret_cast<const float4v*>(&X[(long)(r0 + row) * TD + col]);
        short4v s;
        s[0] = f2bf(x[0]); s[1] = f2bf(x[1]); s[2] = f2bf(x[2]); s[3] = f2bf(x[3]);
        *reinterpret_cast<short4v*>(&xt[row][col]) = s;
    }
    __syncthreads();

    const int n0 = w * 32;
    bf16x8 a[2][4];
#pragma unroll
    for (int mi = 0; mi < 2; ++mi)
#pragma unroll
        for (int kt = 0; kt < 4; ++kt)
            a[mi][kt] = *reinterpret_cast<const bf16x8*>(&xt[mi * 16 + lane16][kt * 32 + g * 8]);

    const f32x4 Z = {0.f, 0.f, 0.f, 0.f};
    f32x4 acc[2][2] = {{Z, Z}, {Z, Z}};
#pragma unroll
    for (int ni = 0; ni < 2; ++ni)
#pragma unroll
        for (int kt = 0; kt < 4; ++kt) {
            bf16x8 b = *reinterpret_cast<const bf16x8*>(
                &Wt[(n0 + ni * 16 + lane16) * TD + kt * 32 + g * 8]);
#pragma unroll
            for (int mi = 0; mi < 2; ++mi)
                acc[mi][ni] = __builtin_amdgcn_mfma_f32_16x16x32_bf16(a[mi][kt], b, acc[mi][ni], 0, 0, 0);
        }

#pragma unroll
    for (int mi = 0; mi < 2; ++mi)
#pragma unroll
        for (int ni = 0; ni < 2; ++ni) {
            int e = n0 + ni * 16 + lane16;
            float bb = bias[e];
#pragma unroll
            for (int reg = 0; reg < 4; ++reg) {
                int row = r0 + mi * 16 + g * 4 + reg;
                Y[(long)row * TD + e] = f2bf(acc[mi][ni][reg] + bb);
            }
        }
}

// ---------------- kernel 2: fused k+v projection ----------------
// k -> bf16 row-major [bq][l][e]; v -> MFMA-fragment-interleaved layout:
//   elem(V[l][e]) at ((((l>>5)*8 + (e>>4))*4 + ((l>>3)&3))*16 + (e&15))*8 + (l&7)
__global__ __launch_bounds__(256) void proj_kv(const float* __restrict__ X,
                                               const short* __restrict__ Wtk,
                                               const float* __restrict__ biask,
                                               const short* __restrict__ Wtv,
                                               const float* __restrict__ biasv,
                                               short* __restrict__ K,
                                               short* __restrict__ Vf) {
    __shared__ short xt[32][136];
    const int t = threadIdx.x;
    const int lane = t & 63, w = t >> 6;
    const int lane16 = lane & 15, g = lane >> 4;
    const int r0 = blockIdx.x * 32;

#pragma unroll
    for (int it = 0; it < 4; ++it) {
        int f4 = t + it * 256;
        int row = f4 >> 5, col = (f4 & 31) * 4;
        float4v x = *reinterpret_cast<const float4v*>(&X[(long)(r0 + row) * TD + col]);
        short4v s;
        s[0] = f2bf(x[0]); s[1] = f2bf(x[1]); s[2] = f2bf(x[2]); s[3] = f2bf(x[3]);
        *reinterpret_cast<short4v*>(&xt[row][col]) = s;
    }
    __syncthreads();

    const int n0 = w * 32;
    bf16x8 a[2][4];
#pragma unroll
    for (int mi = 0; mi < 2; ++mi)
#pragma unroll
        for (int kt = 0; kt < 4; ++kt)
            a[mi][kt] = *reinterpret_cast<const bf16x8*>(&xt[mi * 16 + lane16][kt * 32 + g * 8]);

    const f32x4 Z = {0.f, 0.f, 0.f, 0.f};
    f32x4 ak[2][2] = {{Z, Z}, {Z, Z}};
    f32x4 av[2][2] = {{Z, Z}, {Z, Z}};
#pragma unroll
    for (int ni = 0; ni < 2; ++ni)
#pragma unroll
        for (int kt = 0; kt < 4; ++kt) {
            bf16x8 bk = *reinterpret_cast<const bf16x8*>(
                &Wtk[(n0 + ni * 16 + lane16) * TD + kt * 32 + g * 8]);
            bf16x8 bv = *reinterpret_cast<const bf16x8*>(
                &Wtv[(n0 + ni * 16 + lane16) * TD + kt * 32 + g * 8]);
#pragma unroll
            for (int mi = 0; mi < 2; ++mi) {
                ak[mi][ni] = __builtin_amdgcn_mfma_f32_16x16x32_bf16(a[mi][kt], bk, ak[mi][ni], 0, 0, 0);
                av[mi][ni] = __builtin_amdgcn_mfma_f32_16x16x32_bf16(a[mi][kt], bv, av[mi][ni], 0, 0, 0);
            }
        }

#pragma unroll
    for (int mi = 0; mi < 2; ++mi)
#pragma unroll
        for (int ni = 0; ni < 2; ++ni) {
            int e = n0 + ni * 16 + lane16;
            float bbk = biask[e], bbv = biasv[e];
            // K: row-major
#pragma unroll
            for (int reg = 0; reg < 4; ++reg) {
                int row = r0 + mi * 16 + g * 4 + reg;
                K[(long)row * TD + e] = f2bf(ak[mi][ni][reg] + bbk);
            }
            // V: frag-interleaved (lane holds 4 consecutive l for fixed e)
            int row0 = r0 + mi * 16 + g * 4;   // global source row
            int bq = row0 >> 9;                // /512
            int l = row0 & 511;
            int k32 = l >> 5, j8 = (l >> 3) & 3, jb = l & 7;
            long off = (long)bq * (TL * TD) +
                       ((((long)(k32 * 8 + (e >> 4)) * 4 + j8) * 16) + (e & 15)) * 8 + jb;
            short4v sv;
#pragma unroll
            for (int reg = 0; reg < 4; ++reg) sv[reg] = f2bf(av[mi][ni][reg] + bbv);
            *reinterpret_cast<short4v*>(&Vf[off]) = sv;
        }
}

// ---------------- kernel 3: fused attention (swapped-MFMA, in-register softmax) ----
// block = (b, 32 s-rows), 4 waves; wave w owns l-slice [w*128,(w+1)*128).
// Scores: S^T = mfma(A=K, B=Q): lane holds column s = s0+sg*16+lane16, rows
// l' = 32*(lt>>1)+8g+4*(lt&1)+r via sigma-permuted K row loads -> the held
// set {32kt+8g+j} is EXACTLY the PV A-fragment -> zero cross-lane movement.
// Softmax: lane-local + shfl over g-group; cross-wave via 2KB LDS combine
// (1 barrier/q, double-buffered). o accumulated over q in regs; final 3-barrier
// LDS tree reduction across waves.
__global__ __launch_bounds__(256, 2) void attn_k(const short* __restrict__ qb,
                                                 const short* __restrict__ kb,
                                                 const short* __restrict__ vf,
                                                 short* __restrict__ attn) {
    __shared__ float cmb[2][4][2][16][2];      // [q&1][wave][sg][s-col][max,sum] = 2KB
    __shared__ float red[2][2][8][4][16][4];   // [wpair][sg][et][g][s-col][reg] = 32KB
    const int t = threadIdx.x;
    const int lane = t & 63, w = t >> 6;
    const int lane16 = lane & 15, g = lane >> 4;

    // XCD-aware remap: xcd = idx%8 (dispatch heuristic); give each XCD 2 b's
    // so its K+V working set (4MB) fits the private L2.
    int idx = blockIdx.y * gridDim.x + blockIdx.x;
    int xcd = idx & 7, slot = idx >> 3;
    const int b = xcd * 2 + (slot >> 5);
    const int s0 = (slot & 31) * 32;

    // Q B-fragments for both s-groups, held all kernel
    bf16x8 qf[2][4];
#pragma unroll
    for (int sg = 0; sg < 2; ++sg) {
        const short* qrow = qb + (long)(b * TS + s0 + sg * 16 + lane16) * TD;
#pragma unroll
        for (int kt = 0; kt < 4; ++kt)
            qf[sg][kt] = *reinterpret_cast<const bf16x8*>(qrow + kt * 32 + g * 8);
    }

    const f32x4 Z = {0.f, 0.f, 0.f, 0.f};
    f32x4 o[2][8];
#pragma unroll
    for (int sg = 0; sg < 2; ++sg)
#pragma unroll
        for (int et = 0; et < 8; ++et) o[sg][et] = Z;

    const float C = 0.08838834764831845f * 1.4426950408889634f; // 1/sqrt(128)*log2(e)
    const int arow = 8 * (lane16 >> 2) + (lane16 & 3);          // sigma(lane16) part

    for (int qi = 0; qi < TQ; ++qi) {
        const long kvb = (long)(b * TQ + qi) * (TL * TD);
        const short* Kw = kb + kvb + (long)(w * 128) * TD;

        // ---- scores S^T (K as A, Q as B), sigma-permuted rows ----
        f32x4 sacc[2][8];
#pragma unroll
        for (int sg = 0; sg < 2; ++sg)
#pragma unroll
            for (int lt = 0; lt < 8; ++lt) sacc[sg][lt] = Z;
#pragma unroll
        for (int lt = 0; lt < 8; ++lt) {
            const short* krow = Kw + (long)(32 * (lt >> 1) + 4 * (lt & 1) + arow) * TD;
            bf16x8 ka[4];
#pragma unroll
            for (int kt = 0; kt < 4; ++kt)
                ka[kt] = *reinterpret_cast<const bf16x8*>(krow + kt * 32 + g * 8);
#pragma unroll
            for (int kt = 0; kt < 4; ++kt) {
                sacc[0][lt] = __builtin_amdgcn_mfma_f32_16x16x32_bf16(ka[kt], qf[0][kt], sacc[0][lt], 0, 0, 0);
                sacc[1][lt] = __builtin_amdgcn_mfma_f32_16x16x32_bf16(ka[kt], qf[1][kt], sacc[1][lt], 0, 0, 0);
            }
        }

        // ---- softmax: lane-local + g-group shuffles, wave partials to LDS ----
        float Fs[2];
#pragma unroll
        for (int sg = 0; sg < 2; ++sg) {
            float mx = sacc[sg][0][0];
#pragma unroll
            for (int lt = 0; lt < 8; ++lt)
#pragma unroll
                for (int r = 0; r < 4; ++r) mx = fmaxf(mx, sacc[sg][lt][r]);
            mx = fmaxf(mx, __shfl_xor(mx, 16));
            mx = fmaxf(mx, __shfl_xor(mx, 32));
            float sum = 0.f;
#pragma unroll
            for (int lt = 0; lt < 8; ++lt)
#pragma unroll
                for (int r = 0; r < 4; ++r) {
                    float e = exp2f((sacc[sg][lt][r] - mx) * C);
                    sacc[sg][lt][r] = e;
                    sum += e;
                }
            sum += __shfl_xor(sum, 16);
            sum += __shfl_xor(sum, 32);
            if (lane < 16) {
                cmb[qi & 1][w][sg][lane16][0] = mx;
                cmb[qi & 1][w][sg][lane16][1] = sum;
            }
            Fs[sg] = mx;   // stash wave max
        }
        __syncthreads();
#pragma unroll
        for (int sg = 0; sg < 2; ++sg) {
            float m0 = cmb[qi & 1][0][sg][lane16][0];
            float m1 = cmb[qi & 1][1][sg][lane16][0];
            float m2 = cmb[qi & 1][2][sg][lane16][0];
            float m3 = cmb[qi & 1][3][sg][lane16][0];
            float mg = fmaxf(fmaxf(m0, m1), fmaxf(m2, m3));
            float S = cmb[qi & 1][0][sg][lane16][1] * exp2f((m0 - mg) * C)
                    + cmb[qi & 1][1][sg][lane16][1] * exp2f((m1 - mg) * C)
                    + cmb[qi & 1][2][sg][lane16][1] * exp2f((m2 - mg) * C)
                    + cmb[qi & 1][3][sg][lane16][1] * exp2f((m3 - mg) * C);
            Fs[sg] = exp2f((Fs[sg] - mg) * C) / S;
        }

        // ---- pack P directly into PV A-fragments (zero cross-lane moves) ----
        bf16x8 pa[2][4];
#pragma unroll
        for (int sg = 0; sg < 2; ++sg)
#pragma unroll
            for (int kt = 0; kt < 4; ++kt) {
#pragma unroll
                for (int j = 0; j < 4; ++j)
                    pa[sg][kt][j] = f2bf(sacc[sg][2 * kt][j] * Fs[sg]);
#pragma unroll
                for (int j = 0; j < 4; ++j)
                    pa[sg][kt][4 + j] = f2bf(sacc[sg][2 * kt + 1][j] * Fs[sg]);
            }

        // ---- PV: o[sg][et] += P * V over this wave's l-slice ----
#pragma unroll
        for (int kt = 0; kt < 4; ++kt) {
            const short* vbase = vf + kvb + ((long)(w * 4 + kt) * 4096) + g * 128 + lane16 * 8;
#pragma unroll
            for (int et = 0; et < 8; ++et) {
                bf16x8 vb = *reinterpret_cast<const bf16x8*>(vbase + et * 512);
                o[0][et] = __builtin_amdgcn_mfma_f32_16x16x32_bf16(pa[0][kt], vb, o[0][et], 0, 0, 0);
                o[1][et] = __builtin_amdgcn_mfma_f32_16x16x32_bf16(pa[1][kt], vb, o[1][et], 0, 0, 0);
            }
        }
    }

    // ---- cross-wave o reduction: w2,w3 -> LDS; w0+=red0, w1+=red1; w1 -> LDS; w0 final ----
    if (w >= 2) {
#pragma unroll
        for (int sg = 0; sg < 2; ++sg)
#pragma unroll
            for (int et = 0; et < 8; ++et)
                *reinterpret_cast<f32x4*>(&red[w - 2][sg][et][g][lane16][0]) = o[sg][et];
    }
    __syncthreads();
    if (w < 2) {
#pragma unroll
        for (int sg = 0; sg < 2; ++sg)
#pragma unroll
            for (int et = 0; et < 8; ++et)
                o[sg][et] += *reinterpret_cast<f32x4*>(&red[w][sg][et][g][lane16][0]);
    }
    __syncthreads();
    if (w == 1) {
#pragma unroll
        for (int sg = 0; sg < 2; ++sg)
#pragma unroll
            for (int et = 0; et < 8; ++et)
                *reinterpret_cast<f32x4*>(&red[0][sg][et][g][lane16][0]) = o[sg][et];
    }
    __syncthreads();
    if (w == 0) {
#pragma unroll
        for (int sg = 0; sg < 2; ++sg)
#pragma unroll
            for (int et = 0; et < 8; ++et) {
                o[sg][et] += *reinterpret_cast<f32x4*>(&red[0][sg][et][g][lane16][0]);
#pragma unroll
                for (int reg = 0; reg < 4; ++reg) {
                    int s = s0 + sg * 16 + g * 4 + reg;
                    attn[(long)(b * TS + s) * TD + et * 16 + lane16] = f2bf(o[sg][et][reg]);
                }
            }
    }
}

// ---------------- kernel 4: output projection, f32 out ----------------
__global__ __launch_bounds__(256) void final_proj(const short* __restrict__ A,
                                                  const short* __restrict__ Wt,
                                                  const float* __restrict__ bias,
                                                  float* __restrict__ out) {
    const int t = threadIdx.x;
    const int lane = t & 63, w = t >> 6;
    const int lane16 = lane & 15, g = lane >> 4;
    const int r0 = blockIdx.x * 32;
    const int n0 = w * 32;

    bf16x8 a[2][4];
#pragma unroll
    for (int mi = 0; mi < 2; ++mi)
#pragma unroll
        for (int kt = 0; kt < 4; ++kt)
            a[mi][kt] = *reinterpret_cast<const bf16x8*>(
                &A[(long)(r0 + mi * 16 + lane16) * TD + kt * 32 + g * 8]);

    const f32x4 Z = {0.f, 0.f, 0.f, 0.f};
    f32x4 acc[2][2] = {{Z, Z}, {Z, Z}};
#pragma unroll
    for (int ni = 0; ni < 2; ++ni)
#pragma unroll
        for (int kt = 0; kt < 4; ++kt) {
            bf16x8 b = *reinterpret_cast<const bf16x8*>(
                &Wt[(n0 + ni * 16 + lane16) * TD + kt * 32 + g * 8]);
#pragma unroll
            for (int mi = 0; mi < 2; ++mi)
                acc[mi][ni] = __builtin_amdgcn_mfma_f32_16x16x32_bf16(a[mi][kt], b, acc[mi][ni], 0, 0, 0);
        }

#pragma unroll
    for (int mi = 0; mi < 2; ++mi)
#pragma unroll
        for (int ni = 0; ni < 2; ++ni) {
            int e = n0 + ni * 16 + lane16;
            float bb = bias[e];
#pragma unroll
            for (int reg = 0; reg < 4; ++reg) {
                int row = r0 + mi * 16 + g * 4 + reg;
                out[(long)row * TD + e] = acc[mi][ni][reg] + bb;
            }
        }
}

extern "C" void kernel_launch(void* const* d_in, const int* in_sizes, int n_in,
                              void* d_out, int out_size, void* d_ws, size_t ws_size,
                              hipStream_t stream) {
    (void)in_sizes; (void)n_in; (void)out_size; (void)ws_size;
    const float* target = (const float*)d_in[0];
    const float* source = (const float*)d_in[1];
    const float* Wq = (const float*)d_in[2];
    const float* bq = (const float*)d_in[3];
    const float* Wk = (const float*)d_in[4];
    const float* bk = (const float*)d_in[5];
    const float* Wv = (const float*)d_in[6];
    const float* bv = (const float*)d_in[7];
    const float* Wo = (const float*)d_in[8];
    const float* bo = (const float*)d_in[9];

    char* ws = (char*)d_ws;
    short* qb = (short*)(ws + OFF_Q);
    short* kb = (short*)(ws + OFF_K);
    short* vf = (short*)(ws + OFF_V);
    short* at = (short*)(ws + OFF_ATT);
    short* wt = (short*)(ws + OFF_W);
    float* out = (float*)d_out;

    prep_w<<<4, 256, 0, stream>>>(Wq, Wk, Wv, Wo, wt);
    proj_rm<<<(TB * TS) / 32, 256, 0, stream>>>(target, wt + 0 * TD * TD, bq, qb);
    proj_kv<<<(TB * TQ * TL) / 32, 256, 0, stream>>>(source, wt + 1 * TD * TD, bk,
                                                     wt + 2 * TD * TD, bv, kb, vf);
    dim3 g3(TS / 32, TB);
    attn_k<<<g3, 256, 0, stream>>>(qb, kb, vf, at);
    final_proj<<<(TB * TS) / 32, 256, 0, stream>>>(at, wt + 3 * TD * TD, bo, out);
}